// Round 1
// 703.308 us; speedup vs baseline: 1.0910x; 1.0910x over previous
//
#include <hip/hip_runtime.h>

// ---------------------------------------------------------------------------
// GraphAggregator v2: latency-bound fix.
//  - 64-row blocks (512 thr), acc 64 f32/lane -> regs <=128 -> 2 blocks/CU.
//  - W B-fragments loaded global->VGPR from L2-hot blob (no W LDS, no
//    global_load_lds): LDS = 12.5 KB.
//  - x staged via regs with depth-2 prefetch; main-loop barrier is
//    lgkmcnt-only (raw s_barrier) so x prefetch stays in flight (T4).
//  - pooling: direct exec-masked atomics, no pool LDS, no post-atomic barrier.
// ---------------------------------------------------------------------------

typedef __attribute__((ext_vector_type(8))) short bf16x8;
typedef __attribute__((ext_vector_type(4))) short s16x4;
typedef __attribute__((ext_vector_type(4))) float f32x4;

__device__ __forceinline__ short f2bf(float f) {
  unsigned u = __float_as_uint(f);
  unsigned r = (u + 0x7FFFu + ((u >> 16) & 1u)) >> 16;   // RNE
  return (short)r;
}

__device__ __forceinline__ s16x4 pack4(f32x4 v) {
  s16x4 o;
  o[0] = f2bf(v[0]); o[1] = f2bf(v[1]); o[2] = f2bf(v[2]); o[3] = f2bf(v[3]);
  return o;
}

// ---------------------------------------------------------------------------
// prep_w: fp32 W[k][n] (256x256) -> bf16 blob in MFMA B-fragment order:
//   blob[mat][ks][ct*64+lane][j] = W[ks*32 + (lane>>4)*8 + j][ct*16 + (lane&15)]
// mat 0 = W_gate, mat 1 = W_lin. One block per (mat, ks) slice.  (unchanged)
// ---------------------------------------------------------------------------
__global__ __launch_bounds__(256) void prep_w(const float* __restrict__ Wg,
                                              const float* __restrict__ Wl,
                                              short* __restrict__ blob) {
  __shared__ __align__(16) float tile[32][260];
  const int b = blockIdx.x;
  const int mat = b >> 3, ks = b & 7;
  const float* W = mat ? Wl : Wg;
  const int tid = threadIdx.x;
  #pragma unroll
  for (int i = 0; i < 8; ++i) {
    int f4 = tid + i * 256;
    int kl = f4 >> 6;
    int c0 = (f4 & 63) * 4;
    f32x4 v = *(const f32x4*)&W[(ks * 32 + kl) * 256 + c0];
    tile[kl][c0 + 0] = v[0]; tile[kl][c0 + 1] = v[1];
    tile[kl][c0 + 2] = v[2]; tile[kl][c0 + 3] = v[3];
  }
  __syncthreads();
  #pragma unroll
  for (int i = 0; i < 4; ++i) {
    int chunk = tid + i * 256;           // ct*64 + lane
    int ln = chunk & 63;
    int n  = ((chunk >> 6) << 4) + (ln & 15);
    int k0 = (ln >> 4) * 8;
    bf16x8 o;
    #pragma unroll
    for (int j = 0; j < 8; ++j) o[j] = f2bf(tile[k0 + j][n]);
    *(bf16x8*)&blob[(size_t)(mat * 8 + ks) * 8192 + (size_t)chunk * 8] = o;
  }
}

// ---------------------------------------------------------------------------
// fused_main: 64 rows/block, 512 threads (8 waves), wave = col-group ch
// (32 cols each). Each wave: 4 row-tiles x 2 col-tiles x 2 mats of 16x16.
// ---------------------------------------------------------------------------
__global__ __launch_bounds__(512, 4) void
fused_main(const float* __restrict__ x,
           const int* __restrict__ batch,
           const float* __restrict__ b_lin,
           const float* __restrict__ b_gate,
           const short* __restrict__ blob,
           float* __restrict__ sums) {
  __shared__ __align__(16) short xs[2 * 2048];   // 2 slabs x 64r x 32k bf16 = 8 KB
  __shared__ __align__(16) float pmax[64 * 8];   // [row][wave] 2 KB
  __shared__ __align__(16) float psum[64 * 8];   // 2 KB
  __shared__ int batch_l[64];

  const int tid  = threadIdx.x;
  const int lane = tid & 63;
  const int wave = tid >> 6;            // ch = wave, 0..7 (32 cols each)
  const int quad = lane >> 4;
  const int ln15 = lane & 15;
  const long long row0 = (long long)blockIdx.x * 64;

  // staging decomposition: tid = rt[8:7] m[6:3] q[2:1] h[0]
  const int s_rt = tid >> 7;
  const int s_m  = (tid >> 3) & 15;
  const int s_q  = (tid >> 1) & 3;
  const int s_h  = tid & 1;
  const float* xsrc = x + (row0 + s_rt * 16 + s_m) * 256 + s_q * 8 + s_h * 4;
  const int s_off = (s_rt * 64 + s_q * 16 + s_m) * 8 + s_h * 4;   // shorts

  // prologue: slab0 + slab1 loads in flight; batch tile; write slab0
  f32x4 cur  = __builtin_nontemporal_load((const f32x4*)xsrc);
  f32x4 pend = __builtin_nontemporal_load((const f32x4*)(xsrc + 32));
  if (tid < 64) batch_l[tid] = batch[row0 + tid];
  *(s16x4*)&xs[s_off] = pack4(cur);
  asm volatile("s_waitcnt lgkmcnt(0)\ns_barrier" ::: "memory");

  f32x4 accz[4][2], accs[4][2];
  #pragma unroll
  for (int r = 0; r < 4; ++r)
    #pragma unroll
    for (int c = 0; c < 2; ++c) {
      accz[r][c] = (f32x4)(0.0f);
      accs[r][c] = (f32x4)(0.0f);
    }

  // per-thread invariant part of the B-fragment address
  const short* bptr = blob + (size_t)(wave * 2 * 64 + lane) * 8;

  #pragma unroll
  for (int ks = 0; ks < 8; ++ks) {
    f32x4 nxt;
    if (ks < 6)
      nxt = __builtin_nontemporal_load((const f32x4*)(xsrc + (ks + 2) * 32));
    // B fragments for this ks: direct global (L2-hot blob), 1 KB/wave-instr
    bf16x8 bz0 = *(const bf16x8*)(bptr + (size_t)ks * 8192);
    bf16x8 bz1 = *(const bf16x8*)(bptr + (size_t)ks * 8192 + 512);
    bf16x8 bs0 = *(const bf16x8*)(bptr + (size_t)(8 + ks) * 8192);
    bf16x8 bs1 = *(const bf16x8*)(bptr + (size_t)(8 + ks) * 8192 + 512);
    const short* xb = xs + (ks & 1) * 2048;
    #pragma unroll
    for (int r = 0; r < 4; ++r) {
      bf16x8 a = *(const bf16x8*)(xb + (r * 64 + lane) * 8);
      accz[r][0] = __builtin_amdgcn_mfma_f32_16x16x32_bf16(a, bz0, accz[r][0], 0, 0, 0);
      accz[r][1] = __builtin_amdgcn_mfma_f32_16x16x32_bf16(a, bz1, accz[r][1], 0, 0, 0);
      accs[r][0] = __builtin_amdgcn_mfma_f32_16x16x32_bf16(a, bs0, accs[r][0], 0, 0, 0);
      accs[r][1] = __builtin_amdgcn_mfma_f32_16x16x32_bf16(a, bs1, accs[r][1], 0, 0, 0);
    }
    if (ks < 7)
      *(s16x4*)&xs[((ks + 1) & 1) * 2048 + s_off] = pack4(pend);
    // LDS-only hazard: do NOT drain vmcnt (keeps x prefetch in flight)
    asm volatile("s_waitcnt lgkmcnt(0)\ns_barrier" ::: "memory");
    pend = nxt;
  }

  // biases
  const float bg0 = b_gate[wave * 32 + ln15];
  const float bg1 = b_gate[wave * 32 + 16 + ln15];
  const float bl0 = b_lin [wave * 32 + ln15];
  const float bl1 = b_lin [wave * 32 + 16 + ln15];
  #pragma unroll
  for (int r = 0; r < 4; ++r)
    #pragma unroll
    for (int e = 0; e < 4; ++e) {
      accz[r][0][e] += bg0;
      accz[r][1][e] += bg1;
    }

  // softmax over 256 cols per row (cols split across the 8 waves)
  #pragma unroll
  for (int r = 0; r < 4; ++r)
    #pragma unroll
    for (int e = 0; e < 4; ++e) {
      float v = fmaxf(accz[r][0][e], accz[r][1][e]);
      v = fmaxf(v, __shfl_xor(v, 1));
      v = fmaxf(v, __shfl_xor(v, 2));
      v = fmaxf(v, __shfl_xor(v, 4));
      v = fmaxf(v, __shfl_xor(v, 8));
      if (ln15 == 0) pmax[(r * 16 + quad * 4 + e) * 8 + wave] = v;
    }
  __syncthreads();
  #pragma unroll
  for (int r = 0; r < 4; ++r)
    #pragma unroll
    for (int e = 0; e < 4; ++e) {
      const int rl = r * 16 + quad * 4 + e;
      f32x4 m0 = *(const f32x4*)&pmax[rl * 8];
      f32x4 m1 = *(const f32x4*)&pmax[rl * 8 + 4];
      float fm = fmaxf(fmaxf(fmaxf(m0[0], m0[1]), fmaxf(m0[2], m0[3])),
                       fmaxf(fmaxf(m1[0], m1[1]), fmaxf(m1[2], m1[3])));
      float e0 = __expf(accz[r][0][e] - fm);
      float e1 = __expf(accz[r][1][e] - fm);
      accz[r][0][e] = e0;
      accz[r][1][e] = e1;
      float s = e0 + e1;
      s += __shfl_xor(s, 1);
      s += __shfl_xor(s, 2);
      s += __shfl_xor(s, 4);
      s += __shfl_xor(s, 8);
      if (ln15 == 0) psum[rl * 8 + wave] = s;
    }
  __syncthreads();
  #pragma unroll
  for (int r = 0; r < 4; ++r)
    #pragma unroll
    for (int e = 0; e < 4; ++e) {
      const int rl = r * 16 + quad * 4 + e;
      f32x4 s0 = *(const f32x4*)&psum[rl * 8];
      f32x4 s1 = *(const f32x4*)&psum[rl * 8 + 4];
      float inv = 1.0f / (s0[0] + s0[1] + s0[2] + s0[3] +
                          s1[0] + s1[1] + s1[2] + s1[3]);
      accs[r][0][e] = (accs[r][0][e] + bl0) * (accz[r][0][e] * inv);  // gated
      accs[r][1][e] = (accs[r][1][e] + bl1) * (accz[r][1][e] * inv);
    }

  // segment pooling: masked reduce over rows, quad-shuffle, direct atomics.
  const int b0 = batch_l[0], b1 = batch_l[63];
  for (int g = b0; g <= b1; ++g) {
    float cs0 = 0.0f, cs1 = 0.0f;
    #pragma unroll
    for (int r = 0; r < 4; ++r)
      #pragma unroll
      for (int e = 0; e < 4; ++e) {
        const int rl = r * 16 + quad * 4 + e;
        const float msk = (batch_l[rl] == g) ? 1.0f : 0.0f;
        cs0 = fmaf(accs[r][0][e], msk, cs0);
        cs1 = fmaf(accs[r][1][e], msk, cs1);
      }
    cs0 += __shfl_xor(cs0, 16); cs0 += __shfl_xor(cs0, 32);
    cs1 += __shfl_xor(cs1, 16); cs1 += __shfl_xor(cs1, 32);
    if (quad == 0) {
      atomicAdd(&sums[(size_t)g * 256 + wave * 32 + ln15], cs0);
      atomicAdd(&sums[(size_t)g * 256 + wave * 32 + 16 + ln15], cs1);
    }
  }
}

// ---------------------------------------------------------------------------
// finalize (in-place: io holds per-graph sums on entry, final output on exit)
// ---------------------------------------------------------------------------
__device__ __forceinline__ int lbound(const int* a, int n, int v) {
  int lo = 0, hi = n;
  while (lo < hi) {
    int mid = (lo + hi) >> 1;
    if (a[mid] < v) lo = mid + 1; else hi = mid;
  }
  return lo;
}

__global__ __launch_bounds__(256) void finalize(float* io,
                                                const int* __restrict__ batch, int N,
                                                const float* __restrict__ W_fin,
                                                const float* __restrict__ b_fin) {
  __shared__ __align__(16) float mrow[256];
  __shared__ float s_inv;
  const int g = blockIdx.x, tid = threadIdx.x;
  if (tid == 0) {
    int cnt = lbound(batch, N, g + 1) - lbound(batch, N, g);
    s_inv = 1.0f / fmaxf((float)cnt, 1.0f);
  }
  __syncthreads();
  mrow[tid] = io[(size_t)g * 256 + tid] * s_inv;
  __syncthreads();
  float acc = b_fin[tid];
  #pragma unroll 8
  for (int k = 0; k < 256; ++k)
    acc = fmaf(mrow[k], W_fin[k * 256 + tid], acc);
  io[(size_t)g * 256 + tid] = acc;
}

// ---------------------------------------------------------------------------
extern "C" void kernel_launch(void* const* d_in, const int* in_sizes, int n_in,
                              void* d_out, int out_size, void* d_ws, size_t ws_size,
                              hipStream_t stream) {
  const float* x      = (const float*)d_in[0];
  // d_in[1] = edge_index: unused by the reference
  const int*   batch  = (const int*)d_in[2];     // harness passes integers as int32
  const float* W_lin  = (const float*)d_in[3];
  const float* b_lin  = (const float*)d_in[4];
  const float* W_gate = (const float*)d_in[5];
  const float* b_gate = (const float*)d_in[6];
  const float* W_fin  = (const float*)d_in[7];
  const float* b_fin  = (const float*)d_in[8];
  float* out = (float*)d_out;                    // doubles as the sums buffer
  const int N = in_sizes[2];                     // 400000

  short* blob = (short*)d_ws;                    // 256 KB bf16 weight blob

  hipMemsetAsync(out, 0, (size_t)out_size * sizeof(float), stream);
  prep_w<<<16, 256, 0, stream>>>(W_gate, W_lin, blob);
  fused_main<<<N / 64, 512, 0, stream>>>(x, batch, b_lin, b_gate,
                                         (const short*)blob, out);
  finalize<<<512, 256, 0, stream>>>(out, batch, N, W_fin, b_fin);
}